// Round 9
// baseline (110.735 us; speedup 1.0000x reference)
//
#include <hip/hip_runtime.h>
#include <hip/hip_cooperative_groups.h>
#include <math.h>
#include <stdint.h>

namespace cg = cooperative_groups;

#define K_NN   16
#define BATCH  2
#define NA_    16384
#define NB_    8192
#define CH     128
// coords are [z,y,x]: z in [0,64), y in [0,256), x in [0,256); cell edge 16
#define CZ     4
#define CY     16
#define CX     16
#define NCELL  (CZ*CY*CX)   // 1024
#define CSH    4
#define PADKEY 0xFFF00000u  // > any real key ((134019<<14)|16383 = 0x82E0BFFF)
#define BUILD_BLOCKS 128

__device__ __forceinline__ int cell_of(float p0, float p1, float p2) {
    const int cz = ((int)p0) >> CSH;
    const int cy = ((int)p1) >> CSH;
    const int cx = ((int)p2) >> CSH;
    return (cz * CY + cy) * CX + cx;
}

// ---------------- cooperative fused grid build: zero+count+scan+scatter ----------------

__global__ __launch_bounds__(256) void build_coop(const float* __restrict__ tpos,
                                                  int* __restrict__ counts,   // [B,NCELL] -> cursor
                                                  int2* __restrict__ meta,    // [B,NCELL]
                                                  float4* __restrict__ sorted) {
    cg::grid_group grid = cg::this_grid();
    const int gt = blockIdx.x * 256 + threadIdx.x;
    const int GT = BUILD_BLOCKS * 256;               // 32768

    // zero counts
    if (gt < BATCH * NCELL) counts[gt] = 0;
    grid.sync();

    // histogram (one point per thread; GT == BATCH*NA_)
    {
        const int i = gt;
        const int b = i >> 14;                        // i / NA_
        const float* p = tpos + (size_t)i * 3;
        atomicAdd(&counts[b * NCELL + cell_of(p[0], p[1], p[2])], 1);
    }
    grid.sync();

    // scan: block b scans batch b's 1024 cells (256 threads x 4 cells)
    if (blockIdx.x < BATCH) {
        __shared__ int wp[4];
        const int b = blockIdx.x, t = threadIdx.x;
        const int lane = t & 63, w = t >> 6;
        int* cb = counts + b * NCELL;
        const int4 c4 = *(const int4*)&cb[t * 4];
        const int tsum = c4.x + c4.y + c4.z + c4.w;
        int x = tsum;
#pragma unroll
        for (int off = 1; off < 64; off <<= 1) {
            int u = __shfl_up(x, off);
            if (lane >= off) x += u;
        }
        if (lane == 63) wp[w] = x;
        __syncthreads();
        if (t == 0) {
            int r = 0;
#pragma unroll
            for (int i = 0; i < 4; ++i) { const int v = wp[i]; wp[i] = r; r += v; }
        }
        __syncthreads();
        const int excl = x - tsum + wp[w];
        int2* mbm = meta + b * NCELL;
        const int e0 = excl;
        const int e1 = e0 + c4.x;
        const int e2 = e1 + c4.y;
        const int e3 = e2 + c4.z;
        mbm[t * 4 + 0] = make_int2(e0, c4.x);
        mbm[t * 4 + 1] = make_int2(e1, c4.y);
        mbm[t * 4 + 2] = make_int2(e2, c4.z);
        mbm[t * 4 + 3] = make_int2(e3, c4.w);
        cb[t * 4 + 0] = e0;                           // reuse counts as cursor
        cb[t * 4 + 1] = e1;
        cb[t * 4 + 2] = e2;
        cb[t * 4 + 3] = e3;
    }
    grid.sync();

    // scatter
    {
        const int i = gt;
        const int b = i >> 14;
        const float* p = tpos + (size_t)i * 3;
        const float p0 = p[0], p1 = p[1], p2 = p[2];
        const int cell = cell_of(p0, p1, p2);
        const int pos = atomicAdd(&counts[b * NCELL + cell], 1);
        sorted[(size_t)b * NA_ + pos] =
            make_float4(p0, p1, p2, __int_as_float(i & (NA_ - 1)));
    }
}

// ---------------- exact ring fallback (rare; results -> wave-private LDS) ----------------

__device__ __noinline__ void ring_fallback(int lane, float s0, float s1, float s2,
                                           int scz, int scy, int scx, int rcov,
                                           const int2* __restrict__ mb,
                                           const float4* __restrict__ sb,
                                           uint32_t* selLds) {
    uint32_t sel[K_NN];
#pragma unroll
    for (int j = 0; j < K_NN; ++j) sel[j] = 0xFFFFFFFFu;

    for (int r = 1;; ++r) {
        uint32_t kl[K_NN];
#pragma unroll
        for (int j = 0; j < K_NN; ++j) kl[j] = PADKEY + 16 + j;
        if (r > 1) {
            uint32_t seed = 0xFFFFFFFFu;
#pragma unroll
            for (int j = 0; j < K_NN; ++j) if (lane == j) seed = sel[j];
            kl[0] = seed;
        }
        uint32_t curmax = kl[0];
#pragma unroll
        for (int j = 1; j < K_NN; ++j) curmax = max(curmax, kl[j]);

        for (int dz = -r; dz <= r; ++dz) {
            const int cz = scz + dz; if ((unsigned)cz >= CZ) continue;
            for (int dy = -r; dy <= r; ++dy) {
                const int cy = scy + dy; if ((unsigned)cy >= CY) continue;
                const int rowb = (cz * CY + cy) * CX;
                const bool fullrow = (r == 1) || (max(abs(dz), abs(dy)) == r);
                int xl[2], xh[2];
                if (fullrow) {
                    xl[0] = max(scx - r, 0); xh[0] = min(scx + r, CX - 1);
                    xl[1] = 1; xh[1] = 0;
                } else {
                    xl[0] = scx - r; xh[0] = scx - r;
                    xl[1] = scx + r; xh[1] = scx + r;
                    if (xl[0] < 0)      { xl[0] = 1; xh[0] = 0; }
                    if (xh[1] > CX - 1) { xl[1] = 1; xh[1] = 0; }
                }
#pragma unroll
                for (int q = 0; q < 2; ++q) {
                    if (xl[q] > xh[q]) continue;
                    const int2 mlo = mb[rowb + xl[q]];
                    const int2 mhi = mb[rowb + xh[q]];
                    const int st = mlo.x, ln = mhi.x + mhi.y - st;
                    for (int o = 0; o < ln; o += 64) {
                        const int j2 = o + lane;
                        const bool act = j2 < ln;
                        const int a = st + (act ? j2 : 0);
                        const float4 p = sb[a];
                        const float d0 = s0 - p.x, d1 = s1 - p.y, d2c = s2 - p.z;
                        const float d2 = d0 * d0 + d1 * d1 + d2c * d2c;
                        uint32_t kv = ((uint32_t)d2 << 14) | (uint32_t)__float_as_int(p.w);
                        kv = act ? kv : 0xFFFFFFFFu;
                        if (kv < curmax) {
#pragma unroll
                            for (int j = 0; j < K_NN; ++j)
                                kl[j] = (kl[j] == curmax) ? kv : kl[j];
                            curmax = kl[0];
#pragma unroll
                            for (int j = 1; j < K_NN; ++j) curmax = max(curmax, kl[j]);
                        }
                    }
                }
            }
        }

        uint32_t m = kl[0];
#pragma unroll
        for (int j = 1; j < K_NN; ++j) m = min(m, kl[j]);
#pragma unroll
        for (int rr = 0; rr < K_NN; ++rr) {
            uint32_t v = m;
#pragma unroll
            for (int off = 32; off > 0; off >>= 1)
                v = min(v, (uint32_t)__shfl_xor((int)v, off));
            sel[rr] = (uint32_t)__builtin_amdgcn_readfirstlane((int)v);
            if (m == v) {
#pragma unroll
                for (int j = 0; j < K_NN; ++j) kl[j] = (kl[j] == v) ? 0xFFFFFFFFu : kl[j];
                m = kl[0];
#pragma unroll
                for (int j = 1; j < K_NN; ++j) m = min(m, kl[j]);
            }
        }

        const uint32_t d16 = sel[K_NN - 1] >> 14;
        if (d16 <= (uint32_t)(256 * r * r) || r >= rcov) break;
    }

    if (lane == 0) {
#pragma unroll
        for (int j = 0; j < K_NN; ++j) selLds[j] = sel[j];
    }
}

// ---------------- fast-path helpers ----------------

__device__ __forceinline__ int compact_keys(int lane, const uint32_t (&key)[12],
                                            uint32_t keyT, uint32_t* dst) {
    int nsel = 0;
#pragma unroll
    for (int j = 0; j < 12; ++j) {
        const bool pred = key[j] < keyT;
        const unsigned long long m = __ballot(pred);
        const int offp = __builtin_amdgcn_mbcnt_hi(
            (uint32_t)(m >> 32), __builtin_amdgcn_mbcnt_lo((uint32_t)m, 0));
        if (pred && (nsel + offp) < 132) dst[nsel + offp] = key[j];
        nsel += (int)__builtin_popcountll(m);
    }
    return nsel;
}

__device__ __forceinline__ void rank_write(int lane, const uint32_t* keys, int nsel,
                                           uint32_t* selLds) {
    const uint32_t myk0 = (lane      < nsel) ? keys[lane]      : 0xFFFFFFFFu;
    const uint32_t myk1 = (64 + lane < nsel) ? keys[64 + lane] : 0xFFFFFFFFu;
    uint32_t r0 = 0, r1 = 0;
    const int nmax4 = (nsel + 3) & ~3;
    for (int j = 0; j < nmax4; j += 4) {
        const uint4 k4 = *(const uint4*)&keys[j];
        r0 += (k4.x < myk0) + (k4.y < myk0) + (k4.z < myk0) + (k4.w < myk0);
        r1 += (k4.x < myk1) + (k4.y < myk1) + (k4.z < myk1) + (k4.w < myk1);
    }
    if (r0 < K_NN) selLds[r0] = myk0;
    if (r1 < K_NN) selLds[r1] = myk1;
}

// ---------------- main KNN + aggregation: 1 student/wave, 4 waves/block ----------------

__global__ __launch_bounds__(256) void knn_cells_kernel(
    const float* __restrict__ tfeat,   // [B, NA, C]
    const float* __restrict__ spos,    // [B, NB, 3]
    const int2*  __restrict__ meta,    // [B, NCELL] (start, count)
    const float4* __restrict__ sorted, // [B, NA] (z,y,x,idx-bits)
    float* __restrict__ out)           // [B, NB, C]
{
    __shared__ uint32_t sKeys[4][132];
    __shared__ uint32_t sSel[4][16];

    const int tid  = threadIdx.x;
    const int lane = tid & 63;
    const int wave = tid >> 6;

    const int bpb = NB_ / 4;                    // 2048 blocks per batch
    const int b = blockIdx.x / bpb;
    const int n = (blockIdx.x % bpb) * 4 + wave;

    const int2*   mb = meta   + (size_t)b * NCELL;
    const float4* sb = sorted + (size_t)b * NA_;

    // ---- positions ----
    const float* sp = spos + ((size_t)b * NB_ + n) * 3;
    const float s0 = sp[0], s1 = sp[1], s2 = sp[2];   // z, y, x
    const int scz = __builtin_amdgcn_readfirstlane(((int)s0) >> CSH);
    const int scy = __builtin_amdgcn_readfirstlane(((int)s1) >> CSH);
    const int scx = __builtin_amdgcn_readfirstlane(((int)s2) >> CSH);
    int rcov = max(max(scx, CX - 1 - scx), max(scy, CY - 1 - scy));
    rcov = max(rcov, max(scz, CZ - 1 - scz));

    // ---- 9 row-ranges (wave-uniform) ----
    int rstart[9], rlen[9];
    const int cxlo = max(scx - 1, 0), cxhi = min(scx + 1, CX - 1);
    int nov = 0; bool fast = true;
#pragma unroll
    for (int kk = 0; kk < 9; ++kk) {
        const int cz = scz + kk / 3 - 1, cy = scy + kk % 3 - 1;
        int st = 0, ln = 0;
        if ((unsigned)cz < CZ && (unsigned)cy < CY) {
            const int rowb = (cz * CY + cy) * CX;
            const int2 mlo = mb[rowb + cxlo];
            const int2 mhi = mb[rowb + cxhi];
            st = mlo.x; ln = mhi.x + mhi.y - mlo.x;
        }
        rstart[kk] = st; rlen[kk] = ln;
        if (ln > 64) ++nov;
        if (ln > 128) fast = false;
    }
    if (nov > 3) fast = false;

    // ---- branchless slotted scan ----
    uint32_t key[12];
#pragma unroll
    for (int kk = 0; kk < 9; ++kk) {
        const int ln = rlen[kk];
        const bool act = lane < ln;
        const int a = rstart[kk] + (act ? lane : 0);
        const float4 p = sb[a];
        const float d0 = s0 - p.x, d1 = s1 - p.y, d2c = s2 - p.z;
        const float d2 = d0 * d0 + d1 * d1 + d2c * d2c;
        const uint32_t kv = ((uint32_t)d2 << 14) | (uint32_t)__float_as_int(p.w);
        key[kk] = act ? kv : (PADKEY + kk);
    }
    key[9] = PADKEY + 9; key[10] = PADKEY + 10; key[11] = PADKEY + 11;
    if (nov && fast) {
        int oc = 9;
#pragma unroll
        for (int kk = 0; kk < 9; ++kk) {
            if (rlen[kk] > 64) {
                const int j2 = 64 + lane;
                const bool act = j2 < rlen[kk];
                const int a = rstart[kk] + (act ? j2 : 0);
                const float4 p = sb[a];
                const float d0 = s0 - p.x, d1 = s1 - p.y, d2c = s2 - p.z;
                const float d2 = d0 * d0 + d1 * d1 + d2c * d2c;
                const uint32_t kv = ((uint32_t)d2 << 14) | (uint32_t)__float_as_int(p.w);
                if (oc == 9)       key[9]  = act ? kv : key[9];
                else if (oc == 10) key[10] = act ? kv : key[10];
                else               key[11] = act ? kv : key[11];
                ++oc;
            }
        }
    }

    // ---- two-tier census ----
    const uint32_t KT1 = 169u << 14;
    const uint32_t KT2 = 288u << 14;   // ring-1 stop bound: unexamined >= 289
    uint32_t pc = 0;
#pragma unroll
    for (int j = 0; j < 12; ++j) {
        pc += (key[j] < KT1) ? 1u : 0u;
        pc += (key[j] < KT2) ? 0x10000u : 0u;
    }
#pragma unroll
    for (int off = 32; off > 0; off >>= 1)
        pc += (uint32_t)__shfl_xor((int)pc, off);
    const uint32_t c1 = (uint32_t)__builtin_amdgcn_readfirstlane((int)(pc & 0xFFFFu));
    const uint32_t c2 = (uint32_t)__builtin_amdgcn_readfirstlane((int)(pc >> 16));
    uint32_t keyT = 0;
    if (fast) {
        if (c1 >= K_NN) keyT = KT1;
        else if (c2 >= K_NN) keyT = KT2;
    }

    // ---- compact -> rank -> winners in wave-private LDS ----
    bool ok = false;
    if (keyT) {
        const int nsel = compact_keys(lane, key, keyT, &sKeys[wave][0]);
        ok = (nsel >= K_NN && nsel <= 128);
        if (ok) {
            const int padn = (4 - (nsel & 3)) & 3;
            if (lane < padn) sKeys[wave][nsel + lane] = 0xFFFFFFFFu;
            __threadfence_block();
            rank_write(lane, &sKeys[wave][0], nsel, &sSel[wave][0]);
        }
    }
    if (!ok)
        ring_fallback(lane, s0, s1, s2, scz, scy, scx, rcov, mb, sb, &sSel[wave][0]);
    __threadfence_block();

    // ---- broadcast winners -> wave-uniform registers ----
    const uint4 sA = *(const uint4*)&sSel[wave][0];
    const uint4 sB = *(const uint4*)&sSel[wave][4];
    const uint4 sC = *(const uint4*)&sSel[wave][8];
    const uint4 sD = *(const uint4*)&sSel[wave][12];
    uint32_t sel[K_NN];
    sel[0]  = (uint32_t)__builtin_amdgcn_readfirstlane((int)sA.x);
    sel[1]  = (uint32_t)__builtin_amdgcn_readfirstlane((int)sA.y);
    sel[2]  = (uint32_t)__builtin_amdgcn_readfirstlane((int)sA.z);
    sel[3]  = (uint32_t)__builtin_amdgcn_readfirstlane((int)sA.w);
    sel[4]  = (uint32_t)__builtin_amdgcn_readfirstlane((int)sB.x);
    sel[5]  = (uint32_t)__builtin_amdgcn_readfirstlane((int)sB.y);
    sel[6]  = (uint32_t)__builtin_amdgcn_readfirstlane((int)sB.z);
    sel[7]  = (uint32_t)__builtin_amdgcn_readfirstlane((int)sB.w);
    sel[8]  = (uint32_t)__builtin_amdgcn_readfirstlane((int)sC.x);
    sel[9]  = (uint32_t)__builtin_amdgcn_readfirstlane((int)sC.y);
    sel[10] = (uint32_t)__builtin_amdgcn_readfirstlane((int)sC.z);
    sel[11] = (uint32_t)__builtin_amdgcn_readfirstlane((int)sC.w);
    sel[12] = (uint32_t)__builtin_amdgcn_readfirstlane((int)sD.x);
    sel[13] = (uint32_t)__builtin_amdgcn_readfirstlane((int)sD.y);
    sel[14] = (uint32_t)__builtin_amdgcn_readfirstlane((int)sD.z);
    sel[15] = (uint32_t)__builtin_amdgcn_readfirstlane((int)sD.w);

    // ---- weights + gather (float2 per lane) ----
    float w[K_NN];
    float wsum = 0.f;
#pragma unroll
    for (int j = 0; j < K_NN; ++j) {
        w[j] = __expf(-0.5f * (float)(sel[j] >> 14));
        wsum += w[j];
    }
    const float inv = 1.0f / wsum;

    const float* fb = tfeat + (size_t)b * NA_ * CH;
    float2 acc = make_float2(0.f, 0.f);
#pragma unroll
    for (int j = 0; j < K_NN; ++j) {
        const int idx = (int)(sel[j] & 16383u);
        const float2 v = ((const float2*)(fb + (size_t)idx * CH))[lane];
        const float ww = w[j] * inv;
        acc.x += ww * v.x; acc.y += ww * v.y;
    }

    float2* o = (float2*)(out + ((size_t)b * NB_ + n) * CH);
    o[lane] = acc;
}

// ---------------- launch ----------------

extern "C" void kernel_launch(void* const* d_in, const int* in_sizes, int n_in,
                              void* d_out, int out_size, void* d_ws, size_t ws_size,
                              hipStream_t stream) {
    const float* tfeat = (const float*)d_in[0];   // [B,NA,C]
    const float* tpos  = (const float*)d_in[1];   // [B,NA,3]
    const float* spos  = (const float*)d_in[2];   // [B,NB,3]
    float* out = (float*)d_out;                   // [B,NB,C]

    char* ws = (char*)d_ws;
    int*    counts = (int*)(ws);                  // 2*1024*4  = 8 KiB
    int2*   meta   = (int2*)(ws + 8192);          // 2*1024*8  = 16 KiB
    float4* sorted = (float4*)(ws + 32768);       // 2*16384*16 = 512 KiB

    void* args[] = { (void*)&tpos, (void*)&counts, (void*)&meta, (void*)&sorted };
    hipLaunchCooperativeKernel((const void*)build_coop,
                               dim3(BUILD_BLOCKS), dim3(256), args, 0, stream);
    knn_cells_kernel<<<BATCH * (NB_ / 4), 256, 0, stream>>>(tfeat, spos, meta, sorted, out);
}

// Round 10
// 70.279 us; speedup vs baseline: 1.5756x; 1.5756x over previous
//
#include <hip/hip_runtime.h>
#include <math.h>
#include <stdint.h>

#define K_NN   16
#define BATCH  2
#define NA_    16384
#define NB_    8192
#define CH     128
// coords are [z,y,x]: z in [0,64), y in [0,256), x in [0,256); cell edge 16
#define CZ     4
#define CY     16
#define CX     16
#define NCELL  (CZ*CY*CX)   // 1024
#define CSH    4
#define CAP    32           // bucket capacity; P(Poisson(16)>32) ~ 1e-4 per cell
#define OVFCAP 2048
#define PADKEY 0xFFF00000u  // > any real key ((134019<<14)|16383 = 0x82E0BFFF)

// ws layout:
//   counts : [B][NCELL] int     @ 0       (8 KiB)   (memset to 0 each call)
//   ovfcnt : [B] int            @ 8192    (8 B)     (memset with counts)
//   ovfbuf : [B][OVFCAP] float4 @ 16384   (64 KiB)
//   buckets: [B][NCELL][CAP] f4 @ 81920   (1 MiB)
#define OFF_OVFCNT 8192
#define OFF_OVFBUF 16384
#define OFF_BUCKET 81920

__device__ __forceinline__ int cell_of(float p0, float p1, float p2) {
    const int cz = ((int)p0) >> CSH;
    const int cy = ((int)p1) >> CSH;
    const int cx = ((int)p2) >> CSH;
    return (cz * CY + cy) * CX + cx;
}

// ---------------- one-pass bucketed build ----------------

__global__ __launch_bounds__(256) void bucket_build(const float* __restrict__ tpos,
                                                    int* __restrict__ counts,
                                                    int* __restrict__ ovfcnt,
                                                    float4* __restrict__ ovfbuf,
                                                    float4* __restrict__ buckets) {
    const int i = blockIdx.x * 256 + threadIdx.x;      // over B*NA (= 32768)
    const int b = i >> 14;
    const float* p = tpos + (size_t)i * 3;
    const float p0 = p[0], p1 = p[1], p2 = p[2];
    const int cell = b * NCELL + cell_of(p0, p1, p2);
    const int pos = atomicAdd(&counts[cell], 1);
    const float4 v = make_float4(p0, p1, p2, __int_as_float(i & (NA_ - 1)));
    if (pos < CAP) {
        buckets[(size_t)cell * CAP + pos] = v;
    } else {
        const int o = atomicAdd(&ovfcnt[b], 1);
        if (o < OVFCAP) ovfbuf[b * OVFCAP + o] = v;
    }
}

// ---------------- exact ring fallback (rare; results -> wave-private LDS) ----------------

__device__ __noinline__ void ring_fallback(int lane, float s0, float s1, float s2,
                                           int scz, int scy, int scx, int rcov,
                                           const int* __restrict__ cb,
                                           const float4* __restrict__ bk,
                                           int ovfn, const float4* __restrict__ ovfp,
                                           uint32_t* selLds) {
    uint32_t sel[K_NN];
#pragma unroll
    for (int j = 0; j < K_NN; ++j) sel[j] = 0xFFFFFFFFu;

    for (int r = 1;; ++r) {
        uint32_t kl[K_NN];
#pragma unroll
        for (int j = 0; j < K_NN; ++j) kl[j] = PADKEY + 16 + j;
        if (r > 1) {
            uint32_t seed = 0xFFFFFFFFu;
#pragma unroll
            for (int j = 0; j < K_NN; ++j) if (lane == j) seed = sel[j];
            kl[0] = seed;
        }
        uint32_t curmax = kl[0];
#pragma unroll
        for (int j = 1; j < K_NN; ++j) curmax = max(curmax, kl[j]);

        auto ins = [&](float4 p, bool act) {
            const float d0 = s0 - p.x, d1 = s1 - p.y, d2c = s2 - p.z;
            const float d2 = d0 * d0 + d1 * d1 + d2c * d2c;
            uint32_t kv = ((uint32_t)d2 << 14) | (uint32_t)__float_as_int(p.w);
            kv = act ? kv : 0xFFFFFFFFu;
            if (kv < curmax) {
#pragma unroll
                for (int j = 0; j < K_NN; ++j)
                    kl[j] = (kl[j] == curmax) ? kv : kl[j];
                curmax = kl[0];
#pragma unroll
                for (int j = 1; j < K_NN; ++j) curmax = max(curmax, kl[j]);
            }
        };

        // overflow points: examined once, at r==1 (never "unexamined" afterwards)
        if (r == 1 && ovfn > 0) {
            for (int o = 0; o < ovfn; o += 64) {
                const int j2 = o + lane;
                const bool act = j2 < ovfn;
                ins(ovfp[act ? j2 : 0], act);
            }
        }

        for (int dz = -r; dz <= r; ++dz) {
            const int cz = scz + dz; if ((unsigned)cz >= CZ) continue;
            for (int dy = -r; dy <= r; ++dy) {
                const int cy = scy + dy; if ((unsigned)cy >= CY) continue;
                const int rowb = (cz * CY + cy) * CX;
                const bool fullrow = (r == 1) || (max(abs(dz), abs(dy)) == r);
                int xl[2], xh[2];
                if (fullrow) {
                    xl[0] = max(scx - r, 0); xh[0] = min(scx + r, CX - 1);
                    xl[1] = 1; xh[1] = 0;
                } else {
                    xl[0] = scx - r; xh[0] = scx - r;
                    xl[1] = scx + r; xh[1] = scx + r;
                    if (xl[0] < 0)      { xl[0] = 1; xh[0] = 0; }
                    if (xh[1] > CX - 1) { xl[1] = 1; xh[1] = 0; }
                }
#pragma unroll
                for (int q = 0; q < 2; ++q) {
                    for (int cx = xl[q]; cx <= xh[q]; ++cx) {
                        const int cell = rowb + cx;
                        const int ln = min(cb[cell], CAP);
                        if (ln <= 0) continue;
                        const bool act = lane < ln;
                        ins(bk[(size_t)cell * CAP + (act ? lane : 0)], act);
                    }
                }
            }
        }

        uint32_t m = kl[0];
#pragma unroll
        for (int j = 1; j < K_NN; ++j) m = min(m, kl[j]);
#pragma unroll
        for (int rr = 0; rr < K_NN; ++rr) {
            uint32_t v = m;
#pragma unroll
            for (int off = 32; off > 0; off >>= 1)
                v = min(v, (uint32_t)__shfl_xor((int)v, off));
            sel[rr] = (uint32_t)__builtin_amdgcn_readfirstlane((int)v);
            if (m == v) {
#pragma unroll
                for (int j = 0; j < K_NN; ++j) kl[j] = (kl[j] == v) ? 0xFFFFFFFFu : kl[j];
                m = kl[0];
#pragma unroll
                for (int j = 1; j < K_NN; ++j) m = min(m, kl[j]);
            }
        }

        const uint32_t d16 = sel[K_NN - 1] >> 14;
        if (d16 <= (uint32_t)(256 * r * r) || r >= rcov) break;
    }

    if (lane == 0) {
#pragma unroll
        for (int j = 0; j < K_NN; ++j) selLds[j] = sel[j];
    }
}

// ---------------- fast-path helpers ----------------

__device__ __forceinline__ int compact_keys(int lane, const uint32_t (&key)[12],
                                            uint32_t keyT, uint32_t* dst) {
    int nsel = 0;
#pragma unroll
    for (int j = 0; j < 12; ++j) {
        const bool pred = key[j] < keyT;
        const unsigned long long m = __ballot(pred);
        const int offp = __builtin_amdgcn_mbcnt_hi(
            (uint32_t)(m >> 32), __builtin_amdgcn_mbcnt_lo((uint32_t)m, 0));
        if (pred && (nsel + offp) < 132) dst[nsel + offp] = key[j];
        nsel += (int)__builtin_popcountll(m);
    }
    return nsel;
}

__device__ __forceinline__ void rank_write(int lane, const uint32_t* keys, int nsel,
                                           uint32_t* selLds) {
    const uint32_t myk0 = (lane      < nsel) ? keys[lane]      : 0xFFFFFFFFu;
    const uint32_t myk1 = (64 + lane < nsel) ? keys[64 + lane] : 0xFFFFFFFFu;
    uint32_t r0 = 0, r1 = 0;
    const int nmax4 = (nsel + 3) & ~3;
    for (int j = 0; j < nmax4; j += 4) {
        const uint4 k4 = *(const uint4*)&keys[j];
        r0 += (k4.x < myk0) + (k4.y < myk0) + (k4.z < myk0) + (k4.w < myk0);
        r1 += (k4.x < myk1) + (k4.y < myk1) + (k4.z < myk1) + (k4.w < myk1);
    }
    if (r0 < K_NN) selLds[r0] = myk0;
    if (r1 < K_NN) selLds[r1] = myk1;
}

// ---------------- main KNN + aggregation: 1 student/wave, 4 waves/block ----------------

__global__ __launch_bounds__(256) void knn_cells_kernel(
    const float* __restrict__ tfeat,   // [B, NA, C]
    const float* __restrict__ spos,    // [B, NB, 3]
    const int*   __restrict__ counts,  // [B, NCELL]
    const float4* __restrict__ buckets,// [B, NCELL, CAP]
    const int*   __restrict__ ovfcnt,  // [B]
    const float4* __restrict__ ovfbuf, // [B, OVFCAP]
    float* __restrict__ out)           // [B, NB, C]
{
    __shared__ uint32_t sKeys[4][132];
    __shared__ uint32_t sSel[4][16];

    const int tid  = threadIdx.x;
    const int lane = tid & 63;
    const int wave = tid >> 6;

    const int bpb = NB_ / 4;                    // 2048 blocks per batch
    const int b = blockIdx.x / bpb;
    const int n = (blockIdx.x % bpb) * 4 + wave;

    const int*    cb = counts  + (size_t)b * NCELL;
    const float4* bk = buckets + (size_t)b * NCELL * CAP;
    const int ovfn = __builtin_amdgcn_readfirstlane(ovfcnt[b]);

    // ---- positions ----
    const float* sp = spos + ((size_t)b * NB_ + n) * 3;
    const float s0 = sp[0], s1 = sp[1], s2 = sp[2];   // z, y, x
    const int scz = __builtin_amdgcn_readfirstlane(((int)s0) >> CSH);
    const int scy = __builtin_amdgcn_readfirstlane(((int)s1) >> CSH);
    const int scx = __builtin_amdgcn_readfirstlane(((int)s2) >> CSH);
    int rcov = max(max(scx, CX - 1 - scx), max(scy, CY - 1 - scy));
    rcov = max(rcov, max(scz, CZ - 1 - scz));

    // ---- 9 rows of 2-3 cells: scalar counts + prefix (all wave-uniform) ----
    const int cxlo = max(scx - 1, 0), cxhi = min(scx + 1, CX - 1);
    const int m3 = cxhi - cxlo;                 // 1 -> 2 cells, 2 -> 3 cells
    int rowc[9], rc0[9], rc01[9], rl[9];
    int nov = 0;
    bool fast = (ovfn == 0);
#pragma unroll
    for (int kk = 0; kk < 9; ++kk) {
        const int cz = scz + kk / 3 - 1, cy = scy + kk % 3 - 1;
        int c0 = 0, c1 = 0, c2 = 0, rw = 0;
        if ((unsigned)cz < CZ && (unsigned)cy < CY) {
            rw = (cz * CY + cy) * CX + cxlo;
            c0 = min(cb[rw], CAP);
            c1 = min(cb[rw + 1], CAP);
            if (m3 == 2) c2 = min(cb[rw + 2], CAP);
        }
        rowc[kk] = rw;
        rc0[kk]  = c0;
        rc01[kk] = c0 + c1;
        rl[kk]   = c0 + c1 + c2;
        if (rl[kk] > 64) ++nov;
    }
    if (nov > 3) fast = false;

    // ---- branchless slotted scan over buckets (3-way prefix select) ----
    uint32_t key[12];
#pragma unroll
    for (int kk = 0; kk < 9; ++kk) {
        const bool act = lane < rl[kk];
        const int s = act ? lane : 0;
        const int bsel = (s >= rc0[kk]) + (s >= rc01[kk]);
        const int pref = (bsel == 0) ? 0 : ((bsel == 1) ? rc0[kk] : rc01[kk]);
        const float4 p = bk[(size_t)(rowc[kk] + bsel) * CAP + (s - pref)];
        const float d0 = s0 - p.x, d1 = s1 - p.y, d2c = s2 - p.z;
        const float d2 = d0 * d0 + d1 * d1 + d2c * d2c;
        const uint32_t kv = ((uint32_t)d2 << 14) | (uint32_t)__float_as_int(p.w);
        key[kk] = act ? kv : (PADKEY + kk);
    }
    key[9] = PADKEY + 9; key[10] = PADKEY + 10; key[11] = PADKEY + 11;
    if (nov && fast) {
        int oc = 9;
#pragma unroll
        for (int kk = 0; kk < 9; ++kk) {
            if (rl[kk] > 64) {
                const bool act = (64 + lane) < rl[kk];
                const int s = act ? (64 + lane) : 0;
                const int bsel = (s >= rc0[kk]) + (s >= rc01[kk]);
                const int pref = (bsel == 0) ? 0 : ((bsel == 1) ? rc0[kk] : rc01[kk]);
                const float4 p = bk[(size_t)(rowc[kk] + bsel) * CAP + (s - pref)];
                const float d0 = s0 - p.x, d1 = s1 - p.y, d2c = s2 - p.z;
                const float d2 = d0 * d0 + d1 * d1 + d2c * d2c;
                const uint32_t kv = ((uint32_t)d2 << 14) | (uint32_t)__float_as_int(p.w);
                if (oc == 9)       key[9]  = act ? kv : key[9];
                else if (oc == 10) key[10] = act ? kv : key[10];
                else               key[11] = act ? kv : key[11];
                ++oc;
            }
        }
    }

    // ---- two-tier census ----
    const uint32_t KT1 = 169u << 14;
    const uint32_t KT2 = 288u << 14;   // ring-1 stop bound: unexamined >= 289
    uint32_t pc = 0;
#pragma unroll
    for (int j = 0; j < 12; ++j) {
        pc += (key[j] < KT1) ? 1u : 0u;
        pc += (key[j] < KT2) ? 0x10000u : 0u;
    }
#pragma unroll
    for (int off = 32; off > 0; off >>= 1)
        pc += (uint32_t)__shfl_xor((int)pc, off);
    const uint32_t c1c = (uint32_t)__builtin_amdgcn_readfirstlane((int)(pc & 0xFFFFu));
    const uint32_t c2c = (uint32_t)__builtin_amdgcn_readfirstlane((int)(pc >> 16));
    uint32_t keyT = 0;
    if (fast) {
        if (c1c >= K_NN) keyT = KT1;
        else if (c2c >= K_NN) keyT = KT2;
    }

    // ---- compact -> rank -> winners in wave-private LDS ----
    bool ok = false;
    if (keyT) {
        const int nsel = compact_keys(lane, key, keyT, &sKeys[wave][0]);
        ok = (nsel >= K_NN && nsel <= 128);
        if (ok) {
            const int padn = (4 - (nsel & 3)) & 3;
            if (lane < padn) sKeys[wave][nsel + lane] = 0xFFFFFFFFu;
            __threadfence_block();
            rank_write(lane, &sKeys[wave][0], nsel, &sSel[wave][0]);
        }
    }
    if (!ok)
        ring_fallback(lane, s0, s1, s2, scz, scy, scx, rcov, cb, bk,
                      ovfn, ovfbuf + b * OVFCAP, &sSel[wave][0]);
    __threadfence_block();

    // ---- broadcast winners -> wave-uniform registers ----
    const uint4 sA = *(const uint4*)&sSel[wave][0];
    const uint4 sB = *(const uint4*)&sSel[wave][4];
    const uint4 sC = *(const uint4*)&sSel[wave][8];
    const uint4 sD = *(const uint4*)&sSel[wave][12];
    uint32_t sel[K_NN];
    sel[0]  = (uint32_t)__builtin_amdgcn_readfirstlane((int)sA.x);
    sel[1]  = (uint32_t)__builtin_amdgcn_readfirstlane((int)sA.y);
    sel[2]  = (uint32_t)__builtin_amdgcn_readfirstlane((int)sA.z);
    sel[3]  = (uint32_t)__builtin_amdgcn_readfirstlane((int)sA.w);
    sel[4]  = (uint32_t)__builtin_amdgcn_readfirstlane((int)sB.x);
    sel[5]  = (uint32_t)__builtin_amdgcn_readfirstlane((int)sB.y);
    sel[6]  = (uint32_t)__builtin_amdgcn_readfirstlane((int)sB.z);
    sel[7]  = (uint32_t)__builtin_amdgcn_readfirstlane((int)sB.w);
    sel[8]  = (uint32_t)__builtin_amdgcn_readfirstlane((int)sC.x);
    sel[9]  = (uint32_t)__builtin_amdgcn_readfirstlane((int)sC.y);
    sel[10] = (uint32_t)__builtin_amdgcn_readfirstlane((int)sC.z);
    sel[11] = (uint32_t)__builtin_amdgcn_readfirstlane((int)sC.w);
    sel[12] = (uint32_t)__builtin_amdgcn_readfirstlane((int)sD.x);
    sel[13] = (uint32_t)__builtin_amdgcn_readfirstlane((int)sD.y);
    sel[14] = (uint32_t)__builtin_amdgcn_readfirstlane((int)sD.z);
    sel[15] = (uint32_t)__builtin_amdgcn_readfirstlane((int)sD.w);

    // ---- weights + gather (float2 per lane) ----
    float w[K_NN];
    float wsum = 0.f;
#pragma unroll
    for (int j = 0; j < K_NN; ++j) {
        w[j] = __expf(-0.5f * (float)(sel[j] >> 14));
        wsum += w[j];
    }
    const float inv = 1.0f / wsum;

    const float* fb = tfeat + (size_t)b * NA_ * CH;
    float2 acc = make_float2(0.f, 0.f);
#pragma unroll
    for (int j = 0; j < K_NN; ++j) {
        const int idx = (int)(sel[j] & 16383u);
        const float2 v = ((const float2*)(fb + (size_t)idx * CH))[lane];
        const float ww = w[j] * inv;
        acc.x += ww * v.x; acc.y += ww * v.y;
    }

    float2* o = (float2*)(out + ((size_t)b * NB_ + n) * CH);
    o[lane] = acc;
}

// ---------------- launch ----------------

extern "C" void kernel_launch(void* const* d_in, const int* in_sizes, int n_in,
                              void* d_out, int out_size, void* d_ws, size_t ws_size,
                              hipStream_t stream) {
    const float* tfeat = (const float*)d_in[0];   // [B,NA,C]
    const float* tpos  = (const float*)d_in[1];   // [B,NA,3]
    const float* spos  = (const float*)d_in[2];   // [B,NB,3]
    float* out = (float*)d_out;                   // [B,NB,C]

    char* ws = (char*)d_ws;
    int*    counts  = (int*)(ws);
    int*    ovfcnt  = (int*)(ws + OFF_OVFCNT);
    float4* ovfbuf  = (float4*)(ws + OFF_OVFBUF);
    float4* buckets = (float4*)(ws + OFF_BUCKET);

    // zero counts (8 KiB) + ovfcnt (8 B): contiguous region [0, 8200)
    hipMemsetAsync(ws, 0, OFF_OVFCNT + BATCH * sizeof(int), stream);
    bucket_build<<<(BATCH * NA_) / 256, 256, 0, stream>>>(tpos, counts, ovfcnt,
                                                          ovfbuf, buckets);
    knn_cells_kernel<<<BATCH * (NB_ / 4), 256, 0, stream>>>(tfeat, spos, counts,
                                                            buckets, ovfcnt, ovfbuf, out);
}